// Round 6
// baseline (398.742 us; speedup 1.0000x reference)
//
#include <hip/hip_runtime.h>

#define BATCH   1024
#define MAXLEN  200
#define KCAPS   8
#define INU     256
#define OUTU    256
#define NEGPAD  -65535.0f
#define HSTR    264   // Hi LDS row stride (floats)

typedef _Float16 f16;
typedef _Float16 f16x8 __attribute__((ext_vector_type(8)));
typedef float    f32x4 __attribute__((ext_vector_type(4)));

// ---------------- prep: Bcur copy + S split to hi/lo fp16 (packed frag order)
__global__ void k_prep(const float* __restrict__ S, const float* __restrict__ Bm,
                       f16* __restrict__ Shi, f16* __restrict__ Slo,
                       float* __restrict__ Bcur) {
    int idx = blockIdx.x * 256 + threadIdx.x;    // 0 .. 65535
    if (idx < KCAPS * MAXLEN) Bcur[idx] = Bm[idx];
    int j    = idx & 7;
    int lane = (idx >> 3) & 63;
    int nf   = (idx >> 9) & 15;
    int ks   = idx >> 13;
    int k = ks * 32 + (lane >> 4) * 8 + j;
    int n = nf * 16 + (lane & 15);
    float v = S[k * OUTU + n];
    f16 h = (f16)v;
    Shi[idx] = h;
    Slo[idx] = (f16)(v - (float)h);
}

// ---------------- projection: barrier-free reg-staged split-fp16 MFMA ------
// Block 256 thr = 4 waves; block tile 128x128 (wm=wave>>1 row-half, wn=wave&1
// col-half); wave tile 64x64 (4x4 frags). No LDS, no syncthreads: waves run
// free, unrolled K-loop gives the compiler load-hoisting room; 3 blocks/CU.
__global__ __launch_bounds__(256, 3) void k_project_mfma(const float* __restrict__ A,
                                                         const f16* __restrict__ Shi,
                                                         const f16* __restrict__ Slo,
                                                         float* __restrict__ C) {
    const int tid  = threadIdx.x;
    const int wave = tid >> 6, lane = tid & 63;
    const int wm = wave >> 1, wn = wave & 1;
    const int bm = blockIdx.x >> 1, bc = blockIdx.x & 1;   // col-pairs adjacent -> L2 A-reuse
    const size_t m0 = (size_t)bm * 128 + wm * 64;
    const int n0 = bc * 128 + wn * 64;
    const int r15 = lane & 15, q = lane >> 4;

    const float* ab = A + (m0 + r15) * INU + q * 8;              // + mf*16*INU + ks*32
    const f16* sh = Shi + ((size_t)(bc * 8 + wn * 4) * 512) + lane * 8;  // + ks*8192 + nf*512
    const f16* sl = Slo + ((size_t)(bc * 8 + wn * 4) * 512) + lane * 8;

    f32x4 acc[4][4];
    #pragma unroll
    for (int a = 0; a < 4; a++)
        #pragma unroll
        for (int b = 0; b < 4; b++)
            acc[a][b] = (f32x4){0.f, 0.f, 0.f, 0.f};

    #pragma unroll
    for (int ks = 0; ks < 8; ks++) {
        // A rows for this K-slice (long-latency: issue first)
        f32x4 a0[4], a1[4];
        #pragma unroll
        for (int mf = 0; mf < 4; mf++) {
            const float* ap = ab + (mf * 16) * INU + ks * 32;
            a0[mf] = *reinterpret_cast<const f32x4*>(ap);
            a1[mf] = *reinterpret_cast<const f32x4*>(ap + 4);
        }
        // B frags (L2-resident packed)
        f16x8 bh[4], bl[4];
        #pragma unroll
        for (int nf = 0; nf < 4; nf++) {
            bh[nf] = *reinterpret_cast<const f16x8*>(sh + ks * 8192 + nf * 512);
            bl[nf] = *reinterpret_cast<const f16x8*>(sl + ks * 8192 + nf * 512);
        }
        #pragma unroll
        for (int mf = 0; mf < 4; mf++) {
            f16x8 ah, al;
            #pragma unroll
            for (int j = 0; j < 4; j++) {
                f16 t = (f16)a0[mf][j]; ah[j] = t; al[j] = (f16)(a0[mf][j] - (float)t);
            }
            #pragma unroll
            for (int j = 0; j < 4; j++) {
                f16 t = (f16)a1[mf][j]; ah[4 + j] = t; al[4 + j] = (f16)(a1[mf][j] - (float)t);
            }
            #pragma unroll
            for (int nf = 0; nf < 4; nf++) {
                acc[mf][nf] = __builtin_amdgcn_mfma_f32_16x16x32_f16(ah, bh[nf], acc[mf][nf], 0, 0, 0);
                acc[mf][nf] = __builtin_amdgcn_mfma_f32_16x16x32_f16(al, bh[nf], acc[mf][nf], 0, 0, 0);
                acc[mf][nf] = __builtin_amdgcn_mfma_f32_16x16x32_f16(ah, bl[nf], acc[mf][nf], 0, 0, 0);
            }
        }
    }

    #pragma unroll
    for (int mf = 0; mf < 4; mf++) {
        size_t rbase = m0 + mf * 16 + q * 4;
        #pragma unroll
        for (int nf = 0; nf < 4; nf++) {
            int c = n0 + nf * 16 + r15;
            #pragma unroll
            for (int r = 0; r < 4; r++)
                C[(rbase + r) * OUTU + c] = acc[mf][nf][r];
        }
    }
}

// ---------------- routing iteration (512 threads, len-bounded pass 1) ------
__global__ __launch_bounds__(512) void k_route(const float* __restrict__ Bcur,
                                               const int*   __restrict__ seq_len,
                                               const float* __restrict__ low_new,
                                               float*       __restrict__ partials,
                                               float*       __restrict__ out,
                                               int do_delta, int do_out) {
    __shared__ float Wl[KCAPS * MAXLEN];   // 6.4 KB
    __shared__ float Sl[KCAPS * 256];      // 8 KB  partial-hk slab
    __shared__ float Hi[16 * HSTR];        // 16.9 KB
    const int b   = blockIdx.x;
    const int tid = threadIdx.x;
    const int len = seq_len[b];

    for (int i = tid; i < KCAPS * MAXLEN; i += 512) Wl[i] = Bcur[i];
    for (int i = tid; i < 16 * HSTR; i += 512) Hi[i] = 0.f;
    __syncthreads();

    // masked softmax: one 64-lane wave per k
    {
        const int k  = tid >> 6;
        const int ln = tid & 63;
        float m = -3.4e38f;
        for (int l = ln; l < MAXLEN; l += 64) {
            float v = (l < len) ? Wl[k * MAXLEN + l] : NEGPAD;
            m = fmaxf(m, v);
        }
        #pragma unroll
        for (int off = 32; off >= 1; off >>= 1) m = fmaxf(m, __shfl_xor(m, off));
        float ssum = 0.f;
        for (int l = ln; l < MAXLEN; l += 64) {
            float v = (l < len) ? Wl[k * MAXLEN + l] : NEGPAD;
            ssum += __expf(v - m);
        }
        #pragma unroll
        for (int off = 32; off >= 1; off >>= 1) ssum += __shfl_xor(ssum, off);
        float inv = 1.f / ssum;
        for (int l = ln; l < MAXLEN; l += 64) {
            float v = (l < len) ? Wl[k * MAXLEN + l] : NEGPAD;
            Wl[k * MAXLEN + l] = __expf(v - m) * inv;
        }
    }
    __syncthreads();

    // pass 1: o = tid&255; lg groups interleave 4-l chunks; W==0 for l>=len (len>0)
    const float* lb = low_new + (size_t)b * (MAXLEN * OUTU);
    const int o   = tid & 255;
    const int lg  = tid >> 8;
    const int lim = (len == 0) ? MAXLEN : len;   // len==0 -> uniform W, need all l
    float hk[KCAPS];
    #pragma unroll
    for (int k = 0; k < KCAPS; k++) hk[k] = 0.f;
    for (int l4 = lg * 4; l4 < lim; l4 += 8) {   // max l4=196, reads l4..l4+3 <= 199: safe
        float v0 = lb[(l4 + 0) * OUTU + o];
        float v1 = lb[(l4 + 1) * OUTU + o];
        float v2 = lb[(l4 + 2) * OUTU + o];
        float v3 = lb[(l4 + 3) * OUTU + o];
        #pragma unroll
        for (int k = 0; k < KCAPS; k++) {
            const float4 w = *reinterpret_cast<const float4*>(&Wl[k * MAXLEN + l4]);
            hk[k] = fmaf(w.x, v0, hk[k]);
            hk[k] = fmaf(w.y, v1, hk[k]);
            hk[k] = fmaf(w.z, v2, hk[k]);
            hk[k] = fmaf(w.w, v3, hk[k]);
        }
    }
    if (lg == 1) {
        #pragma unroll
        for (int k = 0; k < KCAPS; k++) Sl[k * 256 + o] = hk[k];
    }
    __syncthreads();

    float scale = 0.f;
    if (lg == 0) {
        float n = 0.f;
        #pragma unroll
        for (int k = 0; k < KCAPS; k++) {
            hk[k] += Sl[k * 256 + o];
            n = fmaf(hk[k], hk[k], n);
        }
        scale = n / (1.f + n) * (1.f / sqrtf(n + 1e-9f));
        if (do_out) {
            #pragma unroll
            for (int k = 0; k < KCAPS; k++)
                out[((size_t)b * KCAPS + k) * OUTU + o] = scale * hk[k];
        }
    }
    if (!do_delta) return;

    if (lg == 0) {
        #pragma unroll
        for (int k = 0; k < KCAPS; k++) Hi[k * HSTR + o] = scale * hk[k];
    }
    __syncthreads();

    // pass 2 (MFMA): delta_T[l][k] = sum_o low[l][o] * high[k][o]; 13 M-frags over 8 waves
    const int wave = tid >> 6, lane = tid & 63;
    const int nfr = (wave < 5) ? 2 : 1;
    f32x4 acc2[2];
    acc2[0] = (f32x4){0.f, 0.f, 0.f, 0.f};
    acc2[1] = (f32x4){0.f, 0.f, 0.f, 0.f};

    for (int ks = 0; ks < 8; ks++) {
        const int ob = ks * 32 + ((lane >> 4) * 8);
        f32x4 h0 = *reinterpret_cast<const f32x4*>(&Hi[(lane & 15) * HSTR + ob]);
        f32x4 h1 = *reinterpret_cast<const f32x4*>(&Hi[(lane & 15) * HSTR + ob + 4]);
        f16x8 bh, bl;
        #pragma unroll
        for (int j = 0; j < 4; j++) {
            f16 t = (f16)h0[j]; bh[j] = t; bl[j] = (f16)(h0[j] - (float)t);
        }
        #pragma unroll
        for (int j = 0; j < 4; j++) {
            f16 t = (f16)h1[j]; bh[4 + j] = t; bl[4 + j] = (f16)(h1[j] - (float)t);
        }
        for (int mi = 0; mi < nfr; mi++) {
            const int mf = wave + mi * 8;
            const int l  = mf * 16 + (lane & 15);      // may exceed 199: garbage row, unwritten
            const float* ap = lb + (size_t)l * OUTU + ob;
            float4 v0 = *reinterpret_cast<const float4*>(ap);
            float4 v1 = *reinterpret_cast<const float4*>(ap + 4);
            f16x8 ah, al;
            ah[0] = (f16)v0.x; al[0] = (f16)(v0.x - (float)ah[0]);
            ah[1] = (f16)v0.y; al[1] = (f16)(v0.y - (float)ah[1]);
            ah[2] = (f16)v0.z; al[2] = (f16)(v0.z - (float)ah[2]);
            ah[3] = (f16)v0.w; al[3] = (f16)(v0.w - (float)ah[3]);
            ah[4] = (f16)v1.x; al[4] = (f16)(v1.x - (float)ah[4]);
            ah[5] = (f16)v1.y; al[5] = (f16)(v1.y - (float)ah[5]);
            ah[6] = (f16)v1.z; al[6] = (f16)(v1.z - (float)ah[6]);
            ah[7] = (f16)v1.w; al[7] = (f16)(v1.w - (float)ah[7]);
            acc2[mi] = __builtin_amdgcn_mfma_f32_16x16x32_f16(ah, bh, acc2[mi], 0, 0, 0);
            acc2[mi] = __builtin_amdgcn_mfma_f32_16x16x32_f16(al, bh, acc2[mi], 0, 0, 0);
            acc2[mi] = __builtin_amdgcn_mfma_f32_16x16x32_f16(ah, bl, acc2[mi], 0, 0, 0);
        }
    }
    const int kcol = lane & 15;
    if (kcol < KCAPS) {
        for (int mi = 0; mi < nfr; mi++) {
            const int mf = wave + mi * 8;
            const int lbase = mf * 16 + ((lane >> 4) * 4);
            #pragma unroll
            for (int r = 0; r < 4; r++) {
                const int l = lbase + r;
                if (l < MAXLEN)
                    partials[(size_t)(kcol * MAXLEN + l) * BATCH + b] = acc2[mi][r];
            }
        }
    }
}

// ---------------- B update ----------------
__global__ __launch_bounds__(256) void k_update(const float* __restrict__ partials,
                                                float* __restrict__ Bcur) {
    __shared__ float red[256];
    const int i   = blockIdx.x;
    const int tid = threadIdx.x;
    float s = 0.f;
    #pragma unroll
    for (int j = 0; j < BATCH / 256; j++) s += partials[(size_t)i * BATCH + tid + j * 256];
    red[tid] = s;
    __syncthreads();
    for (int st = 128; st > 0; st >>= 1) {
        if (tid < st) red[tid] += red[tid + st];
        __syncthreads();
    }
    if (tid == 0) Bcur[i] += red[0];
}

extern "C" void kernel_launch(void* const* d_in, const int* in_sizes, int n_in,
                              void* d_out, int out_size, void* d_ws, size_t ws_size,
                              hipStream_t stream) {
    const float* low = (const float*)d_in[0];
    const float* S   = (const float*)d_in[1];
    const float* Bm  = (const float*)d_in[2];
    const int*   seq = (const int*)d_in[3];
    float* out = (float*)d_out;

    char* ws = (char*)d_ws;
    float* low_new  = (float*)ws;                              // 209,715,200 B
    float* Bcur     = (float*)(ws + 209715200);                // 6,400 B
    float* partials = (float*)(ws + 209721600);                // 6,553,600 B
    f16* Shi = (f16*)(ws + 209721600);                         // aliases partials (projection-only)
    f16* Slo = (f16*)(ws + 209721600 + 131072);

    k_prep<<<256, 256, 0, stream>>>(S, Bm, Shi, Slo, Bcur);
    k_project_mfma<<<3200, 256, 0, stream>>>(low, Shi, Slo, low_new);
    for (int it = 0; it < 3; it++) {
        int last = (it == 2);
        k_route<<<BATCH, 512, 0, stream>>>(Bcur, seq, low_new, partials, out,
                                           last ? 0 : 1, last ? 1 : 0);
        if (!last) k_update<<<KCAPS * MAXLEN, 256, 0, stream>>>(partials, Bcur);
    }
}

// Round 7
// 325.888 us; speedup vs baseline: 1.2236x; 1.2236x over previous
//
#include <hip/hip_runtime.h>

#define BATCH   1024
#define MAXLEN  200
#define KCAPS   8
#define INU     256
#define OUTU    256
#define NEGPAD  -65535.0f
#define HSTR    264   // Hi LDS row stride (floats)

typedef _Float16 f16;
typedef _Float16 f16x8 __attribute__((ext_vector_type(8)));
typedef float    f32x4 __attribute__((ext_vector_type(4)));

__device__ __forceinline__ void gload16(const void* g, void* l) {
    __builtin_amdgcn_global_load_lds(
        (const __attribute__((address_space(1))) void*)g,
        (__attribute__((address_space(3))) void*)l, 16, 0, 0);
}

// ---------------- prep: Bcur copy + S split to hi/lo fp16 (packed frag order)
__global__ void k_prep(const float* __restrict__ S, const float* __restrict__ Bm,
                       f16* __restrict__ Shi, f16* __restrict__ Slo,
                       float* __restrict__ Bcur) {
    int idx = blockIdx.x * 256 + threadIdx.x;    // 0 .. 65535
    if (idx < KCAPS * MAXLEN) Bcur[idx] = Bm[idx];
    int j    = idx & 7;
    int lane = (idx >> 3) & 63;
    int nf   = (idx >> 9) & 15;
    int ks   = idx >> 13;
    int k = ks * 32 + (lane >> 4) * 8 + j;
    int n = nf * 16 + (lane & 15);
    float v = S[k * OUTU + n];
    f16 h = (f16)v;
    Shi[idx] = h;
    Slo[idx] = (f16)(v - (float)h);
}

// ---------------- projection: barrier-free per-wave LDS double-buffer ------
// 256 thr = 4 waves; block tile 128x128; wave tile 64x64. Each wave stages its
// own 64x32 fp32 A-slice via global_load_lds (private region -> NO barriers,
// counted vmcnt survives across K-steps). A.S = Ah.Sh + Al.Sh + Ah.Sl.
#define LW 2048   // floats per wave-buffer (64 rows x 32)

__global__ __launch_bounds__(256, 2) void k_project_mfma(const float* __restrict__ A,
                                                         const f16* __restrict__ Shi,
                                                         const f16* __restrict__ Slo,
                                                         float* __restrict__ C) {
    __shared__ float Af[2][4][LW];   // [buf][wave][64*32] = 64 KB
    const int tid  = threadIdx.x;
    const int wave = tid >> 6, lane = tid & 63;
    const int wm = wave >> 1, wn = wave & 1;
    const int bm = blockIdx.x >> 1, bc = blockIdx.x & 1;   // col-pairs adjacent -> L2 A-reuse
    const size_t m0w = (size_t)bm * 128 + wm * 64;
    const int n0 = bc * 128 + wn * 64;
    const int r15 = lane & 15, q = lane >> 4;

    // staging: chunk i (0..7) covers local rows 8i..8i+7; lane -> row 8i+(lane>>3),
    // 16B at swizzled col (source-side swizzle, LDS stays linear; R5-verified).
    const int sws = ((lane & 7) << 4) ^ (((lane >> 3) & 7) << 4);
    const char* gA = (const char*)A + (m0w + (lane >> 3)) * 1024 + sws;  // +i*8192 +ks*128

    const f16* sh = Shi + ((size_t)(bc * 8 + wn * 4) * 512) + lane * 8;  // +ks*8192 +nf*512
    const f16* sl = Slo + ((size_t)(bc * 8 + wn * 4) * 512) + lane * 8;

    // read-side swizzle constants
    const int rsw  = (lane & 7) << 4;          // row&7 == r15&7 == lane&7 for frag rows
    const int cby0 = (q * 32) ^ rsw;
    const int cby1 = (q * 32 + 16) ^ rsw;

    f32x4 acc[4][4];
    #pragma unroll
    for (int a = 0; a < 4; a++)
        #pragma unroll
        for (int b = 0; b < 4; b++)
            acc[a][b] = (f32x4){0.f, 0.f, 0.f, 0.f};

    // prologue: stage ks=0 -> buf0 (8 x 1KB DMA, this wave's rows only)
    #pragma unroll
    for (int i = 0; i < 8; i++)
        gload16(gA + i * 8192, &Af[0][wave][i * 256]);

    #pragma unroll
    for (int ks = 0; ks < 8; ks++) {
        const int buf = ks & 1;
        // 1) B frags for ks (oldest in queue after this iter's issues)
        f16x8 bh[4], bl[4];
        #pragma unroll
        for (int nf = 0; nf < 4; nf++) {
            bh[nf] = *reinterpret_cast<const f16x8*>(sh + ks * 8192 + nf * 512);
            bl[nf] = *reinterpret_cast<const f16x8*>(sl + ks * 8192 + nf * 512);
        }
        // 2) prefetch A(ks+1) into the other buffer (stays in flight through MFMAs)
        if (ks < 7) {
            #pragma unroll
            for (int i = 0; i < 8; i++)
                gload16(gA + i * 8192 + (ks + 1) * 128, &Af[buf ^ 1][wave][i * 256]);
            // wait for A(ks) DMA (8 oldest); leave B(ks)[8] + A(ks+1)[8] outstanding
            asm volatile("s_waitcnt vmcnt(16)" ::: "memory");
        } else {
            // tail: no prefetch; outstanding = A(7)[8] + B(7)[8] -> retire A(7)
            asm volatile("s_waitcnt vmcnt(8)" ::: "memory");
        }
        __builtin_amdgcn_sched_barrier(0);

        // 3) A frags from this wave's private LDS buffer (swizzled read)
        const char* ab = (const char*)&Af[buf][wave][0];
        #pragma unroll
        for (int mf = 0; mf < 4; mf++) {
            const int row = mf * 16 + r15;
            f32x4 a0 = *reinterpret_cast<const f32x4*>(ab + row * 128 + cby0);
            f32x4 a1 = *reinterpret_cast<const f32x4*>(ab + row * 128 + cby1);
            f16x8 ah, al;
            #pragma unroll
            for (int j = 0; j < 4; j++) {
                f16 t = (f16)a0[j]; ah[j] = t; al[j] = (f16)(a0[j] - (float)t);
            }
            #pragma unroll
            for (int j = 0; j < 4; j++) {
                f16 t = (f16)a1[j]; ah[4 + j] = t; al[4 + j] = (f16)(a1[j] - (float)t);
            }
            #pragma unroll
            for (int nf = 0; nf < 4; nf++) {
                acc[mf][nf] = __builtin_amdgcn_mfma_f32_16x16x32_f16(ah, bh[nf], acc[mf][nf], 0, 0, 0);
                acc[mf][nf] = __builtin_amdgcn_mfma_f32_16x16x32_f16(al, bh[nf], acc[mf][nf], 0, 0, 0);
                acc[mf][nf] = __builtin_amdgcn_mfma_f32_16x16x32_f16(ah, bl[nf], acc[mf][nf], 0, 0, 0);
            }
        }
    }

    #pragma unroll
    for (int mf = 0; mf < 4; mf++) {
        size_t rbase = m0w + mf * 16 + q * 4;
        #pragma unroll
        for (int nf = 0; nf < 4; nf++) {
            int c = n0 + nf * 16 + r15;
            #pragma unroll
            for (int r = 0; r < 4; r++)
                C[(rbase + r) * OUTU + c] = acc[mf][nf][r];
        }
    }
}

// ---------------- routing iteration (512 threads, len-bounded pass 1) ------
__global__ __launch_bounds__(512) void k_route(const float* __restrict__ Bcur,
                                               const int*   __restrict__ seq_len,
                                               const float* __restrict__ low_new,
                                               float*       __restrict__ partials,
                                               float*       __restrict__ out,
                                               int do_delta, int do_out) {
    __shared__ float Wl[KCAPS * MAXLEN];   // 6.4 KB
    __shared__ float Sl[KCAPS * 256];      // 8 KB  partial-hk slab
    __shared__ float Hi[16 * HSTR];        // 16.9 KB
    const int b   = blockIdx.x;
    const int tid = threadIdx.x;
    const int len = seq_len[b];

    for (int i = tid; i < KCAPS * MAXLEN; i += 512) Wl[i] = Bcur[i];
    for (int i = tid; i < 16 * HSTR; i += 512) Hi[i] = 0.f;
    __syncthreads();

    // masked softmax: one 64-lane wave per k
    {
        const int k  = tid >> 6;
        const int ln = tid & 63;
        float m = -3.4e38f;
        for (int l = ln; l < MAXLEN; l += 64) {
            float v = (l < len) ? Wl[k * MAXLEN + l] : NEGPAD;
            m = fmaxf(m, v);
        }
        #pragma unroll
        for (int off = 32; off >= 1; off >>= 1) m = fmaxf(m, __shfl_xor(m, off));
        float ssum = 0.f;
        for (int l = ln; l < MAXLEN; l += 64) {
            float v = (l < len) ? Wl[k * MAXLEN + l] : NEGPAD;
            ssum += __expf(v - m);
        }
        #pragma unroll
        for (int off = 32; off >= 1; off >>= 1) ssum += __shfl_xor(ssum, off);
        float inv = 1.f / ssum;
        for (int l = ln; l < MAXLEN; l += 64) {
            float v = (l < len) ? Wl[k * MAXLEN + l] : NEGPAD;
            Wl[k * MAXLEN + l] = __expf(v - m) * inv;
        }
    }
    __syncthreads();

    // pass 1: o = tid&255; lg groups interleave 4-l chunks; W==0 for l>=len (len>0)
    const float* lb = low_new + (size_t)b * (MAXLEN * OUTU);
    const int o   = tid & 255;
    const int lg  = tid >> 8;
    const int lim = (len == 0) ? MAXLEN : len;   // len==0 -> uniform W, need all l
    float hk[KCAPS];
    #pragma unroll
    for (int k = 0; k < KCAPS; k++) hk[k] = 0.f;
    for (int l4 = lg * 4; l4 < lim; l4 += 8) {   // max l4=196, reads l4..l4+3 <= 199: safe
        float v0 = lb[(l4 + 0) * OUTU + o];
        float v1 = lb[(l4 + 1) * OUTU + o];
        float v2 = lb[(l4 + 2) * OUTU + o];
        float v3 = lb[(l4 + 3) * OUTU + o];
        #pragma unroll
        for (int k = 0; k < KCAPS; k++) {
            const float4 w = *reinterpret_cast<const float4*>(&Wl[k * MAXLEN + l4]);
            hk[k] = fmaf(w.x, v0, hk[k]);
            hk[k] = fmaf(w.y, v1, hk[k]);
            hk[k] = fmaf(w.z, v2, hk[k]);
            hk[k] = fmaf(w.w, v3, hk[k]);
        }
    }
    if (lg == 1) {
        #pragma unroll
        for (int k = 0; k < KCAPS; k++) Sl[k * 256 + o] = hk[k];
    }
    __syncthreads();

    float scale = 0.f;
    if (lg == 0) {
        float n = 0.f;
        #pragma unroll
        for (int k = 0; k < KCAPS; k++) {
            hk[k] += Sl[k * 256 + o];
            n = fmaf(hk[k], hk[k], n);
        }
        scale = n / (1.f + n) * (1.f / sqrtf(n + 1e-9f));
        if (do_out) {
            #pragma unroll
            for (int k = 0; k < KCAPS; k++)
                out[((size_t)b * KCAPS + k) * OUTU + o] = scale * hk[k];
        }
    }
    if (!do_delta) return;

    if (lg == 0) {
        #pragma unroll
        for (int k = 0; k < KCAPS; k++) Hi[k * HSTR + o] = scale * hk[k];
    }
    __syncthreads();

    // pass 2 (MFMA): delta_T[l][k] = sum_o low[l][o] * high[k][o]; 13 M-frags over 8 waves
    const int wave = tid >> 6, lane = tid & 63;
    const int nfr = (wave < 5) ? 2 : 1;
    f32x4 acc2[2];
    acc2[0] = (f32x4){0.f, 0.f, 0.f, 0.f};
    acc2[1] = (f32x4){0.f, 0.f, 0.f, 0.f};

    for (int ks = 0; ks < 8; ks++) {
        const int ob = ks * 32 + ((lane >> 4) * 8);
        f32x4 h0 = *reinterpret_cast<const f32x4*>(&Hi[(lane & 15) * HSTR + ob]);
        f32x4 h1 = *reinterpret_cast<const f32x4*>(&Hi[(lane & 15) * HSTR + ob + 4]);
        f16x8 bh, bl;
        #pragma unroll
        for (int j = 0; j < 4; j++) {
            f16 t = (f16)h0[j]; bh[j] = t; bl[j] = (f16)(h0[j] - (float)t);
        }
        #pragma unroll
        for (int j = 0; j < 4; j++) {
            f16 t = (f16)h1[j]; bh[4 + j] = t; bl[4 + j] = (f16)(h1[j] - (float)t);
        }
        for (int mi = 0; mi < nfr; mi++) {
            const int mf = wave + mi * 8;
            const int l  = mf * 16 + (lane & 15);      // may exceed 199: garbage row, unwritten
            const float* ap = lb + (size_t)l * OUTU + ob;
            float4 v0 = *reinterpret_cast<const float4*>(ap);
            float4 v1 = *reinterpret_cast<const float4*>(ap + 4);
            f16x8 ah, al;
            ah[0] = (f16)v0.x; al[0] = (f16)(v0.x - (float)ah[0]);
            ah[1] = (f16)v0.y; al[1] = (f16)(v0.y - (float)ah[1]);
            ah[2] = (f16)v0.z; al[2] = (f16)(v0.z - (float)ah[2]);
            ah[3] = (f16)v0.w; al[3] = (f16)(v0.w - (float)ah[3]);
            ah[4] = (f16)v1.x; al[4] = (f16)(v1.x - (float)ah[4]);
            ah[5] = (f16)v1.y; al[5] = (f16)(v1.y - (float)ah[5]);
            ah[6] = (f16)v1.z; al[6] = (f16)(v1.z - (float)ah[6]);
            ah[7] = (f16)v1.w; al[7] = (f16)(v1.w - (float)ah[7]);
            acc2[mi] = __builtin_amdgcn_mfma_f32_16x16x32_f16(ah, bh, acc2[mi], 0, 0, 0);
            acc2[mi] = __builtin_amdgcn_mfma_f32_16x16x32_f16(al, bh, acc2[mi], 0, 0, 0);
            acc2[mi] = __builtin_amdgcn_mfma_f32_16x16x32_f16(ah, bl, acc2[mi], 0, 0, 0);
        }
    }
    const int kcol = lane & 15;
    if (kcol < KCAPS) {
        for (int mi = 0; mi < nfr; mi++) {
            const int mf = wave + mi * 8;
            const int lbase = mf * 16 + ((lane >> 4) * 4);
            #pragma unroll
            for (int r = 0; r < 4; r++) {
                const int l = lbase + r;
                if (l < MAXLEN)
                    partials[(size_t)(kcol * MAXLEN + l) * BATCH + b] = acc2[mi][r];
            }
        }
    }
}

// ---------------- B update ----------------
__global__ __launch_bounds__(256) void k_update(const float* __restrict__ partials,
                                                float* __restrict__ Bcur) {
    __shared__ float red[256];
    const int i   = blockIdx.x;
    const int tid = threadIdx.x;
    float s = 0.f;
    #pragma unroll
    for (int j = 0; j < BATCH / 256; j++) s += partials[(size_t)i * BATCH + tid + j * 256];
    red[tid] = s;
    __syncthreads();
    for (int st = 128; st > 0; st >>= 1) {
        if (tid < st) red[tid] += red[tid + st];
        __syncthreads();
    }
    if (tid == 0) Bcur[i] += red[0];
}

extern "C" void kernel_launch(void* const* d_in, const int* in_sizes, int n_in,
                              void* d_out, int out_size, void* d_ws, size_t ws_size,
                              hipStream_t stream) {
    const float* low = (const float*)d_in[0];
    const float* S   = (const float*)d_in[1];
    const float* Bm  = (const float*)d_in[2];
    const int*   seq = (const int*)d_in[3];
    float* out = (float*)d_out;

    char* ws = (char*)d_ws;
    float* low_new  = (float*)ws;                              // 209,715,200 B
    float* Bcur     = (float*)(ws + 209715200);                // 6,400 B
    float* partials = (float*)(ws + 209721600);                // 6,553,600 B
    f16* Shi = (f16*)(ws + 209721600);                         // aliases partials (projection-only)
    f16* Slo = (f16*)(ws + 209721600 + 131072);

    k_prep<<<256, 256, 0, stream>>>(S, Bm, Shi, Slo, Bcur);
    k_project_mfma<<<3200, 256, 0, stream>>>(low, Shi, Slo, low_new);
    for (int it = 0; it < 3; it++) {
        int last = (it == 2);
        k_route<<<BATCH, 512, 0, stream>>>(Bcur, seq, low_new, partials, out,
                                           last ? 0 : 1, last ? 1 : 0);
        if (!last) k_update<<<KCAPS * MAXLEN, 256, 0, stream>>>(partials, Bcur);
    }
}